// Round 12
// baseline (332.571 us; speedup 1.0000x reference)
//
#include <hip/hip_runtime.h>
#include <hip/hip_bf16.h>
#include <math.h>

#define T_TOK 2048
#define DIM 512
#define HID 1024
#define NE 8
#define CAP 1024
#define GRID 512

typedef __attribute__((ext_vector_type(8))) short short8;
typedef __attribute__((ext_vector_type(4))) float floatx4;

__device__ __forceinline__ unsigned short f2bf_bits(float f) {
    __hip_bfloat16 h = __float2bfloat16(f);
    return *reinterpret_cast<unsigned short*>(&h);
}

__device__ __forceinline__ void gl2lds(const unsigned short* g, unsigned short* l) {
    __builtin_amdgcn_global_load_lds(
        (const __attribute__((address_space(1))) unsigned int*)g,
        (__attribute__((address_space(3))) unsigned int*)l, 16, 0, 0);
}

__device__ __forceinline__ short8 frag(const unsigned short* s, int row, int kg) {
    return *reinterpret_cast<const short8*>(s + row * 128 + (((kg) ^ (row & 7)) << 3));
}

template<int T>
__device__ __forceinline__ void stage_tile(const unsigned short* src, size_t RS,
                                           int k0, unsigned short* lds,
                                           int wave, int lane) {
    int ro = lane >> 4, gr = lane & 15;
#pragma unroll
    for (int i = wave; i < T / 4; i += 4) {
        int r = i * 4 + ro;
        gl2lds(src + (size_t)r * RS + k0 + (((gr ^ (r & 7)) << 3)),
               lds + i * 512);
    }
}

// producer release: all block stores done -> fence -> flag++
__device__ __forceinline__ void release_inc(int* flag, int tid) {
    __syncthreads();
    if (tid == 0) { __threadfence(); atomicAdd(flag, 1); }
}
// consumer acquire: spin flag==target -> fence -> barrier
__device__ __forceinline__ void acquire_wait(int* flag, int target, int tid) {
    if (tid == 0) {
        while (atomicAdd(flag, 0) != target) {}
        __threadfence();
    }
    __syncthreads();
}

// Flags in ws[0..4096): counts @0 (e*64B), routerDone @1024, castDone[96] @1280,
// h1done[128] @2048, g2total @2560.
__global__ __launch_bounds__(256, 2)
void moe_mega(const float* __restrict__ x, const float* __restrict__ wr,
              const float* __restrict__ br, const float* __restrict__ w1,
              const float* __restrict__ w2,
              unsigned short* __restrict__ w1b, unsigned short* __restrict__ w2b,
              unsigned short* __restrict__ xg, int* __restrict__ flags,
              int2* __restrict__ pairSlot, float2* __restrict__ pw,
              unsigned short* __restrict__ Hb, float* __restrict__ ybuf,
              float* __restrict__ out, float* __restrict__ logits_out) {
    __shared__ __align__(16) unsigned short s_a[64 * 128];    // 16 KB
    __shared__ __align__(16) unsigned short s_b[128 * 128];   // 32 KB

    int* counts     = flags;
    int* routerDone = flags + 256;
    int* castDone   = flags + 320;
    int* h1done     = flags + 512;
    int* g2total    = flags + 640;

    const int bx = blockIdx.x, tid = threadIdx.x;
    const int wave = tid >> 6, lane = tid & 63;
    const int g = lane >> 4, ln = lane & 15;
    const int wm = wave & 1, wn = wave >> 1;

    // ================= Phase A: router (bx<128) | weight cast (bx>=128) ========
    if (bx < 128) {
        for (int it = 0; it < 4; it++) {
            int t = bx * 16 + it * 4 + wave;
            const float4* xr = reinterpret_cast<const float4*>(x + (size_t)t * DIM);
            float4 xa = xr[lane * 2], xc = xr[lane * 2 + 1];
            short8 o;
            o[0] = (short)f2bf_bits(xa.x); o[1] = (short)f2bf_bits(xa.y);
            o[2] = (short)f2bf_bits(xa.z); o[3] = (short)f2bf_bits(xa.w);
            o[4] = (short)f2bf_bits(xc.x); o[5] = (short)f2bf_bits(xc.y);
            o[6] = (short)f2bf_bits(xc.z); o[7] = (short)f2bf_bits(xc.w);
            float p[NE];
#pragma unroll
            for (int e = 0; e < NE; e++) {
                const float4* wre = reinterpret_cast<const float4*>(wr + e * DIM);
                float4 wa = wre[lane * 2], wc = wre[lane * 2 + 1];
                p[e] = xa.x * wa.x + xa.y * wa.y + xa.z * wa.z + xa.w * wa.w
                     + xc.x * wc.x + xc.y * wc.y + xc.z * wc.z + xc.w * wc.w;
            }
#pragma unroll
            for (int e = 0; e < NE; e++) {
#pragma unroll
                for (int off = 32; off >= 1; off >>= 1)
                    p[e] += __shfl_xor(p[e], off, 64);
            }
            int slot1 = 0, slot2 = 0;
            if (lane == 0) {
                float l[NE];
#pragma unroll
                for (int e = 0; e < NE; e++) {
                    l[e] = p[e] + br[e];
                    logits_out[(size_t)t * NE + e] = l[e];
                }
                int e1 = 0;
#pragma unroll
                for (int e = 1; e < NE; e++) if (l[e] > l[e1]) e1 = e;
                int es = -1;
#pragma unroll
                for (int e = 0; e < NE; e++) {
                    if (e == e1) continue;
                    if (es < 0 || l[e] > l[es]) es = e;
                }
                float z = expf(l[es] - l[e1]);
                float inv = 1.f / (1.f + z);
                int pos1 = atomicAdd(&counts[e1 * 16], 1);
                if (pos1 > CAP - 1) pos1 = CAP - 1;
                int pos2 = atomicAdd(&counts[es * 16], 1);
                if (pos2 > CAP - 1) pos2 = CAP - 1;
                slot1 = e1 * CAP + pos1;
                slot2 = es * CAP + pos2;
                pairSlot[t] = make_int2(slot1, slot2);
                pw[t] = make_float2(inv, z * inv);
            }
            slot1 = __shfl(slot1, 0);
            slot2 = __shfl(slot2, 0);
            *reinterpret_cast<short8*>(xg + (size_t)slot1 * DIM + lane * 8) = o;
            *reinterpret_cast<short8*>(xg + (size_t)slot2 * DIM + lane * 8) = o;
        }
        release_inc(routerDone, tid);
    } else {
        int sj = bx - 128;            // 0..383
        int tile = sj >> 2, q = sj & 3;
        if (tile < 64) {
            // w1 tile (e, ni): 128 rows; quarter = 32 rows x 512
            int e = tile >> 3, ni = tile & 7;
            size_t base = (size_t)(e * HID + ni * 128 + q * 32) * DIM;
            const float4* s = reinterpret_cast<const float4*>(w1 + base);
            ushort4* d = reinterpret_cast<ushort4*>(w1b + base);
#pragma unroll
            for (int k = 0; k < 16; k++) {
                float4 v = s[k * 256 + tid];
                ushort4 o;
                o.x = f2bf_bits(v.x); o.y = f2bf_bits(v.y);
                o.z = f2bf_bits(v.z); o.w = f2bf_bits(v.w);
                d[k * 256 + tid] = o;
            }
        } else {
            // w2 tile (e, ni4): 128 rows; quarter = 32 rows x 1024
            int u = tile - 64;
            int e = u >> 2, ni = u & 3;
            size_t base = (size_t)(e * DIM + ni * 128 + q * 32) * HID;
            const float4* s = reinterpret_cast<const float4*>(w2 + base);
            ushort4* d = reinterpret_cast<ushort4*>(w2b + base);
#pragma unroll
            for (int k = 0; k < 32; k++) {
                float4 v = s[k * 256 + tid];
                ushort4 o;
                o.x = f2bf_bits(v.x); o.y = f2bf_bits(v.y);
                o.z = f2bf_bits(v.z); o.w = f2bf_bits(v.w);
                d[k * 256 + tid] = o;
            }
        }
        release_inc(&castDone[tile], tid);
    }

    // ================= Phase B: gemm1, jobs {bx, bx+512} =======================
#pragma unroll
    for (int rep = 0; rep < 2; rep++) {
        int job = bx + rep * 512;
        int e = job & 7, rest = job >> 3;
        int ni = rest & 7, mi = rest >> 3;
        acquire_wait(routerDone, 128, tid);
        acquire_wait(&castDone[e * 8 + ni], 4, tid);
        int cnt = counts[e * 16]; if (cnt > CAP) cnt = CAP;
        int m0 = mi * 64, n0 = ni * 128;
        if (m0 < cnt) {
            const unsigned short* asrc = xg + (size_t)(e * CAP + m0) * DIM;
            const unsigned short* bsrc = w1b + (size_t)(e * HID + n0) * DIM;
            floatx4 acc[2][4];
#pragma unroll
            for (int mf = 0; mf < 2; mf++)
#pragma unroll
                for (int nf = 0; nf < 4; nf++) acc[mf][nf] = (floatx4){0.f, 0.f, 0.f, 0.f};
            for (int ph = 0; ph < 4; ph++) {
                int k0 = ph * 128;
                stage_tile<64>(asrc, DIM, k0, s_a, wave, lane);
                stage_tile<128>(bsrc, DIM, k0, s_b, wave, lane);
                __syncthreads();
#pragma unroll
                for (int ks = 0; ks < 4; ks++) {
                    short8 a0 = frag(s_a, wm * 32 + ln, ks * 4 + g);
                    short8 a1 = frag(s_a, wm * 32 + 16 + ln, ks * 4 + g);
#pragma unroll
                    for (int nf = 0; nf < 4; nf++) {
                        short8 b = frag(s_b, wn * 64 + nf * 16 + ln, ks * 4 + g);
                        acc[0][nf] = __builtin_amdgcn_mfma_f32_16x16x32_bf16(a0, b, acc[0][nf], 0, 0, 0);
                        acc[1][nf] = __builtin_amdgcn_mfma_f32_16x16x32_bf16(a1, b, acc[1][nf], 0, 0, 0);
                    }
                }
                __syncthreads();
            }
#pragma unroll
            for (int mf = 0; mf < 2; mf++)
#pragma unroll
                for (int nf = 0; nf < 4; nf++)
#pragma unroll
                    for (int r = 0; r < 4; r++) {
                        int lr = wm * 32 + mf * 16 + g * 4 + r;
                        int col = n0 + wn * 64 + nf * 16 + ln;
                        float v = acc[mf][nf][r];
                        float gv = 0.5f * v * (1.f + erff(v * 0.70710678118f));
                        Hb[(size_t)(e * CAP + m0 + lr) * HID + col] = f2bf_bits(gv);
                    }
        }
        release_inc(&h1done[e * 16 + mi], tid);
    }

    // ================= Phase C: gemm2, jobs {bx, bx+512} =======================
#pragma unroll
    for (int rep = 0; rep < 2; rep++) {
        int job = bx + rep * 512;
        int e = job & 7, rest = job >> 3;
        int ni = rest & 3, kv = (rest >> 2) & 1, mi = rest >> 3;
        acquire_wait(&h1done[e * 16 + mi], 8, tid);
        acquire_wait(&castDone[64 + e * 4 + ni], 4, tid);
        int cnt = counts[e * 16]; if (cnt > CAP) cnt = CAP;
        int m0 = mi * 64, n0 = ni * 128;
        if (m0 < cnt) {
            const unsigned short* asrc = Hb + (size_t)(e * CAP + m0) * HID;
            const unsigned short* bsrc = w2b + (size_t)(e * DIM + n0) * HID;
            floatx4 acc[2][4];
#pragma unroll
            for (int mf = 0; mf < 2; mf++)
#pragma unroll
                for (int nf = 0; nf < 4; nf++) acc[mf][nf] = (floatx4){0.f, 0.f, 0.f, 0.f};
            for (int ph = 0; ph < 4; ph++) {
                int k0 = kv * 512 + ph * 128;
                stage_tile<64>(asrc, HID, k0, s_a, wave, lane);
                stage_tile<128>(bsrc, HID, k0, s_b, wave, lane);
                __syncthreads();
#pragma unroll
                for (int ks = 0; ks < 4; ks++) {
                    short8 a0 = frag(s_a, wm * 32 + ln, ks * 4 + g);
                    short8 a1 = frag(s_a, wm * 32 + 16 + ln, ks * 4 + g);
#pragma unroll
                    for (int nf = 0; nf < 4; nf++) {
                        short8 b = frag(s_b, wn * 64 + nf * 16 + ln, ks * 4 + g);
                        acc[0][nf] = __builtin_amdgcn_mfma_f32_16x16x32_bf16(a0, b, acc[0][nf], 0, 0, 0);
                        acc[1][nf] = __builtin_amdgcn_mfma_f32_16x16x32_bf16(a1, b, acc[1][nf], 0, 0, 0);
                    }
                }
                __syncthreads();
            }
            float* yb = ybuf + (size_t)kv * (NE * CAP * DIM);
#pragma unroll
            for (int mf = 0; mf < 2; mf++)
#pragma unroll
                for (int nf = 0; nf < 4; nf++)
#pragma unroll
                    for (int r = 0; r < 4; r++) {
                        int lr = wm * 32 + mf * 16 + g * 4 + r;
                        int col = n0 + wn * 64 + nf * 16 + ln;
                        yb[(size_t)(e * CAP + m0 + lr) * DIM + col] = acc[mf][nf][r];
                    }
        }
        release_inc(g2total, tid);
    }

    // ================= Phase D: combine ========================================
    acquire_wait(g2total, 1024, tid);
    const size_t KV = (size_t)NE * CAP * DIM;
#pragma unroll
    for (int rep = 0; rep < 2; rep++) {
        int id = bx * 512 + rep * 256 + tid;   // 262144 float4 total
        int t = id >> 7, dv = id & 127;
        int2 s = pairSlot[t];
        float2 w = pw[t];
        const float4* y0a = reinterpret_cast<const float4*>(ybuf + (size_t)s.x * DIM);
        const float4* y1a = reinterpret_cast<const float4*>(ybuf + KV + (size_t)s.x * DIM);
        const float4* y0b = reinterpret_cast<const float4*>(ybuf + (size_t)s.y * DIM);
        const float4* y1b = reinterpret_cast<const float4*>(ybuf + KV + (size_t)s.y * DIM);
        float4 a = y0a[dv], b = y1a[dv], c = y0b[dv], d = y1b[dv];
        float4 r;
        r.x = w.x * (a.x + b.x) + w.y * (c.x + d.x);
        r.y = w.x * (a.y + b.y) + w.y * (c.y + d.y);
        r.z = w.x * (a.z + b.z) + w.y * (c.z + d.z);
        r.w = w.x * (a.w + b.w) + w.y * (c.w + d.w);
        reinterpret_cast<float4*>(out)[(size_t)t * 128 + dv] = r;
    }
}

extern "C" void kernel_launch(void* const* d_in, const int* in_sizes, int n_in,
                              void* d_out, int out_size, void* d_ws, size_t ws_size,
                              hipStream_t stream) {
    const float* x  = (const float*)d_in[0];
    const float* wr = (const float*)d_in[1];
    const float* br = (const float*)d_in[2];
    const float* w1 = (const float*)d_in[3];
    const float* w2 = (const float*)d_in[4];
    float* out = (float*)d_out;
    float* logits_out = out + (size_t)T_TOK * DIM;

    char* ws = (char*)d_ws;
    int*    flags    = (int*)ws;                                // 4 KB (counts+flags)
    int2*   pairSlot = (int2*)(ws + 4096);                      // 16 KB
    float2* pw       = (float2*)(ws + 24576);                   // 16 KB
    unsigned short* xg  = (unsigned short*)(ws + 131072);       // 8 MB
    unsigned short* w1b = (unsigned short*)(ws + 8519680);      // 8 MB
    unsigned short* w2b = (unsigned short*)(ws + 16908288);     // 8 MB
    unsigned short* Hb  = (unsigned short*)(ws + 25296896);     // 16 MB
    float*          ybuf = (float*)(ws + 42074112);             // 32 MB

    hipMemsetAsync(flags, 0, 4096, stream);

    moe_mega<<<GRID, 256, 0, stream>>>(x, wr, br, w1, w2, w1b, w2b, xg,
                                       flags, pairSlot, pw, Hb, ybuf,
                                       out, logits_out);
}

// Round 13
// 128.960 us; speedup vs baseline: 2.5789x; 2.5789x over previous
//
#include <hip/hip_runtime.h>
#include <hip/hip_bf16.h>
#include <math.h>

#define T_TOK 2048
#define DIM 512
#define HID 1024
#define NE 8
#define CAP 1024

#define ROUT_BLKS 128
#define CAST_BLKS 2048

typedef __attribute__((ext_vector_type(8))) short short8;
typedef __attribute__((ext_vector_type(4))) float floatx4;

__device__ __forceinline__ unsigned short f2bf_bits(float f) {
    __hip_bfloat16 h = __float2bfloat16(f);
    return *reinterpret_cast<unsigned short*>(&h);
}

__device__ __forceinline__ void gl2lds(const unsigned short* g, unsigned short* l) {
    __builtin_amdgcn_global_load_lds(
        (const __attribute__((address_space(1))) unsigned int*)g,
        (__attribute__((address_space(3))) unsigned int*)l, 16, 0, 0);
}

// LDS frag read: packed [row][128] shorts (BK=128), granule kg of row r at kg^(r&7)
__device__ __forceinline__ short8 frag(const unsigned short* s, int row, int kg) {
    return *reinterpret_cast<const short8*>(s + row * 128 + (((kg) ^ (row & 7)) << 3));
}

// stage T rows (k-slice of 128 = 256 B/row) into packed swizzled LDS
template<int T>
__device__ __forceinline__ void stage_tile(const unsigned short* src, size_t RS,
                                           int k0, unsigned short* lds,
                                           int wave, int lane) {
    int ro = lane >> 4, gr = lane & 15;
#pragma unroll
    for (int i = wave; i < T / 4; i += 4) {
        int r = i * 4 + ro;
        gl2lds(src + (size_t)r * RS + k0 + (((gr ^ (r & 7)) << 3)),
               lds + i * 512);
    }
}

// ---------------- prep: router+gather (blocks 0..127) | weight cast ----------------
__global__ __launch_bounds__(256)
void prep(const float* __restrict__ x, const float* __restrict__ wr,
          const float* __restrict__ br,
          const float* __restrict__ w1, const float* __restrict__ w2,
          unsigned short* __restrict__ w1b, unsigned short* __restrict__ w2b,
          unsigned short* __restrict__ xg, int* __restrict__ counts,
          int2* __restrict__ pairSlot, float2* __restrict__ pw,
          float* __restrict__ logits_out) {
    int bx = blockIdx.x;
    int tid = threadIdx.x;
    if (bx >= ROUT_BLKS) {
        const int n1 = NE * HID * DIM / 4;
        int base = (bx - ROUT_BLKS) * 1024 + tid;
#pragma unroll
        for (int rep = 0; rep < 4; rep++) {
            int i = base + rep * 256;
            const float* s = (i < n1) ? w1 : w2;
            unsigned short* d = (i < n1) ? w1b : w2b;
            int j = (i < n1) ? i : i - n1;
            float4 v = reinterpret_cast<const float4*>(s)[j];
            ushort4 o;
            o.x = f2bf_bits(v.x); o.y = f2bf_bits(v.y);
            o.z = f2bf_bits(v.z); o.w = f2bf_bits(v.w);
            reinterpret_cast<ushort4*>(d)[j] = o;
        }
        return;
    }
    int wave = tid >> 6, lane = tid & 63;
    for (int it = 0; it < 4; it++) {
        int t = bx * 16 + it * 4 + wave;
        const float4* xr = reinterpret_cast<const float4*>(x + (size_t)t * DIM);
        float4 xa = xr[lane * 2], xc = xr[lane * 2 + 1];
        short8 o;
        o[0] = (short)f2bf_bits(xa.x); o[1] = (short)f2bf_bits(xa.y);
        o[2] = (short)f2bf_bits(xa.z); o[3] = (short)f2bf_bits(xa.w);
        o[4] = (short)f2bf_bits(xc.x); o[5] = (short)f2bf_bits(xc.y);
        o[6] = (short)f2bf_bits(xc.z); o[7] = (short)f2bf_bits(xc.w);
        float p[NE];
#pragma unroll
        for (int e = 0; e < NE; e++) {
            const float4* wre = reinterpret_cast<const float4*>(wr + e * DIM);
            float4 wa = wre[lane * 2], wc = wre[lane * 2 + 1];
            p[e] = xa.x * wa.x + xa.y * wa.y + xa.z * wa.z + xa.w * wa.w
                 + xc.x * wc.x + xc.y * wc.y + xc.z * wc.z + xc.w * wc.w;
        }
#pragma unroll
        for (int e = 0; e < NE; e++) {
#pragma unroll
            for (int off = 32; off >= 1; off >>= 1)
                p[e] += __shfl_xor(p[e], off, 64);
        }
        int slot1 = 0, slot2 = 0;
        if (lane == 0) {
            float l[NE];
#pragma unroll
            for (int e = 0; e < NE; e++) {
                l[e] = p[e] + br[e];
                logits_out[(size_t)t * NE + e] = l[e];
            }
            int e1 = 0;
#pragma unroll
            for (int e = 1; e < NE; e++) if (l[e] > l[e1]) e1 = e;
            int es = -1;
#pragma unroll
            for (int e = 0; e < NE; e++) {
                if (e == e1) continue;
                if (es < 0 || l[e] > l[es]) es = e;
            }
            float z = expf(l[es] - l[e1]);
            float inv = 1.f / (1.f + z);
            int pos1 = atomicAdd(&counts[e1 * 16], 1);
            if (pos1 > CAP - 1) pos1 = CAP - 1;
            int pos2 = atomicAdd(&counts[es * 16], 1);
            if (pos2 > CAP - 1) pos2 = CAP - 1;
            slot1 = e1 * CAP + pos1;
            slot2 = es * CAP + pos2;
            pairSlot[t] = make_int2(slot1, slot2);
            pw[t] = make_float2(inv, z * inv);
        }
        slot1 = __shfl(slot1, 0);
        slot2 = __shfl(slot2, 0);
        *reinterpret_cast<short8*>(xg + (size_t)slot1 * DIM + lane * 8) = o;
        *reinterpret_cast<short8*>(xg + (size_t)slot2 * DIM + lane * 8) = o;
    }
}

// ---------------- GEMM1: H = gelu(Xg @ W1^T) ----------------
// Block 64m x 64n, K=512 in 4 phases of BK=128. 4 waves (2x2, wave-tile 32x32).
// LDS 32 KB -> 4 blocks/CU; grid 2048, ~1024 active = 4/CU.
__global__ __launch_bounds__(256, 4)
void gemm1(const unsigned short* __restrict__ xg,
           const unsigned short* __restrict__ w1b,
           const int* __restrict__ counts,
           unsigned short* __restrict__ Hb) {
    int bx = blockIdx.x;
    int e = bx & 7;                       // XCD affinity
    int rest = bx >> 3;
    int n0 = (rest & 15) * 64;            // 16 n-tiles
    int m0 = (rest >> 4) * 64;            // 16 m-tiles
    int cnt = counts[e * 16]; if (cnt > CAP) cnt = CAP;
    if (m0 >= cnt) return;

    __shared__ __align__(16) unsigned short s_a[64 * 128];   // 16 KB
    __shared__ __align__(16) unsigned short s_b[64 * 128];   // 16 KB

    int tid = threadIdx.x, wave = tid >> 6, lane = tid & 63;
    int g = lane >> 4, ln = lane & 15;
    int wm = wave & 1, wn = wave >> 1;

    const unsigned short* asrc = xg + (size_t)(e * CAP + m0) * DIM;
    const unsigned short* bsrc = w1b + (size_t)(e * HID + n0) * DIM;

    floatx4 acc[2][2];
#pragma unroll
    for (int mf = 0; mf < 2; mf++)
#pragma unroll
        for (int nf = 0; nf < 2; nf++) acc[mf][nf] = (floatx4){0.f, 0.f, 0.f, 0.f};

    for (int ph = 0; ph < 4; ph++) {
        int k0 = ph * 128;
        stage_tile<64>(asrc, DIM, k0, s_a, wave, lane);
        stage_tile<64>(bsrc, DIM, k0, s_b, wave, lane);
        __syncthreads();
#pragma unroll
        for (int ks = 0; ks < 4; ks++) {
            short8 a0 = frag(s_a, wm * 32 + ln, ks * 4 + g);
            short8 a1 = frag(s_a, wm * 32 + 16 + ln, ks * 4 + g);
            short8 b0 = frag(s_b, wn * 32 + ln, ks * 4 + g);
            short8 b1 = frag(s_b, wn * 32 + 16 + ln, ks * 4 + g);
            acc[0][0] = __builtin_amdgcn_mfma_f32_16x16x32_bf16(a0, b0, acc[0][0], 0, 0, 0);
            acc[1][0] = __builtin_amdgcn_mfma_f32_16x16x32_bf16(a1, b0, acc[1][0], 0, 0, 0);
            acc[0][1] = __builtin_amdgcn_mfma_f32_16x16x32_bf16(a0, b1, acc[0][1], 0, 0, 0);
            acc[1][1] = __builtin_amdgcn_mfma_f32_16x16x32_bf16(a1, b1, acc[1][1], 0, 0, 0);
        }
        __syncthreads();
    }
#pragma unroll
    for (int mf = 0; mf < 2; mf++)
#pragma unroll
        for (int nf = 0; nf < 2; nf++)
#pragma unroll
            for (int r = 0; r < 4; r++) {
                int lr = wm * 32 + mf * 16 + g * 4 + r;
                int col = n0 + wn * 32 + nf * 16 + ln;
                float v = acc[mf][nf][r];
                float gv = 0.5f * v * (1.f + erff(v * 0.70710678118f));
                Hb[(size_t)(e * CAP + m0 + lr) * HID + col] = f2bf_bits(gv);
            }
}

// ---------------- GEMM2: ybuf[kv] = H @ W2^T (plain stores) ----------------
__global__ __launch_bounds__(256, 4)
void gemm2(const unsigned short* __restrict__ Hb,
           const unsigned short* __restrict__ w2b,
           const int* __restrict__ counts,
           float* __restrict__ ybuf) {
    int bx = blockIdx.x;
    int e = bx & 7;
    int rest = bx >> 3;
    int n0 = (rest & 7) * 64;             // 8 n-tiles
    int kv = (rest >> 3) & 1;
    int m0 = (rest >> 4) * 64;            // 16 m-tiles
    int cnt = counts[e * 16]; if (cnt > CAP) cnt = CAP;
    if (m0 >= cnt) return;

    __shared__ __align__(16) unsigned short s_a[64 * 128];
    __shared__ __align__(16) unsigned short s_b[64 * 128];

    int tid = threadIdx.x, wave = tid >> 6, lane = tid & 63;
    int g = lane >> 4, ln = lane & 15;
    int wm = wave & 1, wn = wave >> 1;

    const unsigned short* asrc = Hb + (size_t)(e * CAP + m0) * HID;
    const unsigned short* bsrc = w2b + (size_t)(e * DIM + n0) * HID;

    floatx4 acc[2][2];
#pragma unroll
    for (int mf = 0; mf < 2; mf++)
#pragma unroll
        for (int nf = 0; nf < 2; nf++) acc[mf][nf] = (floatx4){0.f, 0.f, 0.f, 0.f};

    for (int ph = 0; ph < 4; ph++) {
        int k0 = kv * 512 + ph * 128;
        stage_tile<64>(asrc, HID, k0, s_a, wave, lane);
        stage_tile<64>(bsrc, HID, k0, s_b, wave, lane);
        __syncthreads();
#pragma unroll
        for (int ks = 0; ks < 4; ks++) {
            short8 a0 = frag(s_a, wm * 32 + ln, ks * 4 + g);
            short8 a1 = frag(s_a, wm * 32 + 16 + ln, ks * 4 + g);
            short8 b0 = frag(s_b, wn * 32 + ln, ks * 4 + g);
            short8 b1 = frag(s_b, wn * 32 + 16 + ln, ks * 4 + g);
            acc[0][0] = __builtin_amdgcn_mfma_f32_16x16x32_bf16(a0, b0, acc[0][0], 0, 0, 0);
            acc[1][0] = __builtin_amdgcn_mfma_f32_16x16x32_bf16(a1, b0, acc[1][0], 0, 0, 0);
            acc[0][1] = __builtin_amdgcn_mfma_f32_16x16x32_bf16(a0, b1, acc[0][1], 0, 0, 0);
            acc[1][1] = __builtin_amdgcn_mfma_f32_16x16x32_bf16(a1, b1, acc[1][1], 0, 0, 0);
        }
        __syncthreads();
    }
    float* yb = ybuf + (size_t)kv * (NE * CAP * DIM);
#pragma unroll
    for (int mf = 0; mf < 2; mf++)
#pragma unroll
        for (int nf = 0; nf < 2; nf++)
#pragma unroll
            for (int r = 0; r < 4; r++) {
                int lr = wm * 32 + mf * 16 + g * 4 + r;
                int col = n0 + wn * 32 + nf * 16 + ln;
                yb[(size_t)(e * CAP + m0 + lr) * DIM + col] = acc[mf][nf][r];
            }
}

// ---------------- combine ----------------
__global__ __launch_bounds__(256)
void combine_kernel(const float* __restrict__ ybuf, const int2* __restrict__ pairSlot,
                    const float2* __restrict__ pw, float* __restrict__ out) {
    int id = blockIdx.x * 256 + threadIdx.x;   // 262144 float4
    int t = id >> 7, dv = id & 127;
    int2 s = pairSlot[t];
    float2 w = pw[t];
    const size_t KV = (size_t)NE * CAP * DIM;
    const float4* y0a = reinterpret_cast<const float4*>(ybuf + (size_t)s.x * DIM);
    const float4* y1a = reinterpret_cast<const float4*>(ybuf + KV + (size_t)s.x * DIM);
    const float4* y0b = reinterpret_cast<const float4*>(ybuf + (size_t)s.y * DIM);
    const float4* y1b = reinterpret_cast<const float4*>(ybuf + KV + (size_t)s.y * DIM);
    float4 a = y0a[dv], b = y1a[dv], c = y0b[dv], d = y1b[dv];
    float4 r;
    r.x = w.x * (a.x + b.x) + w.y * (c.x + d.x);
    r.y = w.x * (a.y + b.y) + w.y * (c.y + d.y);
    r.z = w.x * (a.z + b.z) + w.y * (c.z + d.z);
    r.w = w.x * (a.w + b.w) + w.y * (c.w + d.w);
    reinterpret_cast<float4*>(out)[(size_t)t * 128 + dv] = r;
}

extern "C" void kernel_launch(void* const* d_in, const int* in_sizes, int n_in,
                              void* d_out, int out_size, void* d_ws, size_t ws_size,
                              hipStream_t stream) {
    const float* x  = (const float*)d_in[0];
    const float* wr = (const float*)d_in[1];
    const float* br = (const float*)d_in[2];
    const float* w1 = (const float*)d_in[3];
    const float* w2 = (const float*)d_in[4];
    float* out = (float*)d_out;
    float* logits_out = out + (size_t)T_TOK * DIM;

    char* ws = (char*)d_ws;
    int*    counts   = (int*)ws;                                // 512 B (x16 padded)
    int2*   pairSlot = (int2*)(ws + 4096);                      // 16 KB
    float2* pw       = (float2*)(ws + 24576);                   // 16 KB
    unsigned short* xg  = (unsigned short*)(ws + 131072);       // 8 MB
    unsigned short* w1b = (unsigned short*)(ws + 8519680);      // 8 MB
    unsigned short* w2b = (unsigned short*)(ws + 16908288);     // 8 MB
    unsigned short* Hb  = (unsigned short*)(ws + 25296896);     // 16 MB
    float*          ybuf = (float*)(ws + 42074112);             // 32 MB

    hipMemsetAsync(counts, 0, 512, stream);

    prep<<<ROUT_BLKS + CAST_BLKS, 256, 0, stream>>>(
        x, wr, br, w1, w2, w1b, w2b, xg, counts, pairSlot, pw, logits_out);

    // 8e x 16m x 16n = 2048 blocks (~1024 active = 4/CU)
    gemm1<<<NE * 16 * 16, 256, 0, stream>>>(xg, w1b, counts, Hb);

    // 8e x 16m x 2kv x 8n = 2048 blocks (~1024 active = 4/CU)
    gemm2<<<NE * 16 * 2 * 8, 256, 0, stream>>>(Hb, w2b, counts, ybuf);

    combine_kernel<<<1024, 256, 0, stream>>>(ybuf, pairSlot, pw, out);
}